// Round 4
// baseline (211.778 us; speedup 1.0000x reference)
//
#include <hip/hip_runtime.h>
#include <hip/hip_bf16.h>
#include <hip/hip_fp16.h>

#define Bn 2048
#define Tn 128
#define Vn 256
#define Cn 32
#define Hn 128
#define En 256
#define On 256
#define Gn 384
#define BNn 32

typedef _Float16 f16;
typedef __attribute__((ext_vector_type(8))) _Float16 h8;
typedef __attribute__((ext_vector_type(4))) _Float16 h4;
typedef __attribute__((ext_vector_type(4))) float f4;

#define LOG2E 1.4426950408889634f

__device__ __forceinline__ float fexp2(float x) { return __builtin_amdgcn_exp2f(x); }
__device__ __forceinline__ float frcp(float x) { return __builtin_amdgcn_rcpf(x); }

// ---------------- Kernel 1: packed scaled xp table ----------------
// xt[dir][v][j][4] = { -log2e*(xr+bir), -log2e*(xz+biz), 2log2e*(xn+bin), 0 }
__global__ void build_table_k(const float* __restrict__ emb,
                              const float* __restrict__ wf,
                              const float* __restrict__ bfv,
                              const float* __restrict__ wb,
                              const float* __restrict__ bbv,
                              f16* __restrict__ xt) {
  const int dir = blockIdx.x >> 8;
  const int v = blockIdx.x & 255;
  const int j = threadIdx.x;  // 128 threads
  const float* w = dir ? wb : wf;
  const float* bi = dir ? bbv : bfv;
  const float sc[3] = {-LOG2E, -LOG2E, 2.0f * LOG2E};
  h4 o;
  o[3] = (f16)0.f;
#pragma unroll
  for (int ga = 0; ga < 3; ++ga) {
    const int g = ga * Hn + j;
    float acc = bi[g];
    const f4* wr = (const f4*)(w + g * Cn);
    const f4* er = (const f4*)(emb + v * Cn);
#pragma unroll
    for (int q = 0; q < 8; ++q) {
      f4 wv = wr[q], ev = er[q];
      acc = fmaf(ev.x, wv.x, acc);
      acc = fmaf(ev.y, wv.y, acc);
      acc = fmaf(ev.z, wv.z, acc);
      acc = fmaf(ev.w, wv.w, acc);
    }
    o[ga] = (f16)(acc * sc[ga]);
  }
  *(h4*)&xt[((dir * Vn + v) * Hn + j) * 4] = o;
}

// ---------------- Kernel 2: bidirectional GRU ----------------
// 512 blocks: dir = bi&1, 8 samples/block (MFMA rows 8-15 zero), 4 waves x 32 j.
// h fragment-major: byte(k,m) = (k>>3)*256 + m*16 + (k&7)*2, double-buffered.
// xp prefetched to REGISTERS one step ahead (no LDS staging).
__launch_bounds__(256, 2)
__global__ void gru_k(const int* __restrict__ tokens,
                      const float* __restrict__ whhf,
                      const float* __restrict__ bhhf,
                      const float* __restrict__ whhb,
                      const float* __restrict__ bhhb,
                      const f16* __restrict__ xt,
                      float* __restrict__ feat) {
  const int dir = blockIdx.x & 1;
  const int b0 = (blockIdx.x >> 1) * 8;
  const int tid = threadIdx.x;
  const int wv = tid >> 6;   // 0..3
  const int ln = tid & 63;
  const int lr = ln & 15;    // A row (sample m) / C col (j within tile)
  const int lg = ln >> 4;    // 0..3 : k-group; C rows m = lg*4+r (valid m<8 -> lg<2)
  const int j0 = wv * 32;

  __shared__ f16 hfrag[2 * 2048];  // 2 x 4KB: [16 kq][16 m][8 ke]
  __shared__ int tokl[8 * 128];

  for (int i = tid; i < 8 * 128; i += 256)
    tokl[i] = tokens[(b0 + (i >> 7)) * Tn + (i & 127)];
  for (int i = tid; i < 2 * 2048; i += 256) hfrag[i] = (f16)0.f;

  const float* whh = dir ? whhb : whhf;
  const float* bhh = dir ? bhhb : bhhf;
  const f16* tab = xt + dir * (Vn * Hn * 4);

  // register-resident B frags (2 jtiles x 3 gates x 4 kk), gate-scaled
  const float gsc[3] = {-LOG2E, -LOG2E, 2.0f * LOG2E};
  h8 Bf[2][3][4];
  float bh[2][3];
#pragma unroll
  for (int jt = 0; jt < 2; ++jt) {
    const int j = j0 + jt * 16 + lr;
#pragma unroll
    for (int ga = 0; ga < 3; ++ga) {
      const float* wr = whh + (ga * Hn + j) * Hn + lg * 8;
#pragma unroll
      for (int kk = 0; kk < 4; ++kk) {
        h8 b;
#pragma unroll
        for (int i = 0; i < 8; ++i) b[i] = (f16)(wr[kk * 32 + i] * gsc[ga]);
        Bf[jt][ga][kk] = b;
      }
      bh[jt][ga] = bhh[ga * Hn + j] * gsc[ga];
    }
  }

  __syncthreads();  // tokl + hfrag zero visible

  const int aoff = lg * 256 + lr * 16;  // A-frag byte offset (+ kk*1024)
  int wo[2];
#pragma unroll
  for (int jt = 0; jt < 2; ++jt) {
    const int j = j0 + jt * 16 + lr;
    wo[jt] = (j >> 3) * 256 + (j & 7) * 2 + lg * 64;  // + r*16
  }
  const int sbase = (lg & 1) * 4;  // sample row base for this lane's m&7

  h4 xc[8], xn[8];
#pragma unroll
  for (int i = 0; i < 8; ++i) xc[i] = (h4)0;

  // prefetch xp for t=0 (valid lanes only; halves L2 traffic)
  if (lg < 2) {
    const int tt = dir ? (Tn - 1) : 0;
#pragma unroll
    for (int r = 0; r < 4; ++r) {
      const int tok = tokl[(sbase + r) * 128 + tt];
      xc[r] = *(const h4*)(tab + tok * 512 + (j0 + lr) * 4);
      xc[4 + r] = *(const h4*)(tab + tok * 512 + (j0 + 16 + lr) * 4);
    }
  }

  float hprev[8] = {0.f, 0.f, 0.f, 0.f, 0.f, 0.f, 0.f, 0.f};
  int p = 0;

  for (int t = 0; t < Tn; ++t) {
    // prefetch xp(t+1) into registers
    const int tn = (t + 1 < Tn) ? (t + 1) : t;
    const int tt2 = dir ? (Tn - 1 - tn) : tn;
    if (lg < 2) {
#pragma unroll
      for (int r = 0; r < 4; ++r) {
        const int tok = tokl[(sbase + r) * 128 + tt2];
        xn[r] = *(const h4*)(tab + tok * 512 + (j0 + lr) * 4);
        xn[4 + r] = *(const h4*)(tab + tok * 512 + (j0 + 16 + lr) * 4);
      }
    }

    // gh = h @ w_hh^T + b_hh
    const char* hb = (const char*)hfrag + p * 4096;
    f4 acc[2][3];
#pragma unroll
    for (int jt = 0; jt < 2; ++jt)
#pragma unroll
      for (int ga = 0; ga < 3; ++ga)
        acc[jt][ga] = (f4){bh[jt][ga], bh[jt][ga], bh[jt][ga], bh[jt][ga]};
#pragma unroll
    for (int kk = 0; kk < 4; ++kk) {
      h8 a = *(const h8*)(hb + kk * 1024 + aoff);
#pragma unroll
      for (int jt = 0; jt < 2; ++jt) {
        acc[jt][0] = __builtin_amdgcn_mfma_f32_16x16x32_f16(a, Bf[jt][0][kk], acc[jt][0], 0, 0, 0);
        acc[jt][1] = __builtin_amdgcn_mfma_f32_16x16x32_f16(a, Bf[jt][1][kk], acc[jt][1], 0, 0, 0);
        acc[jt][2] = __builtin_amdgcn_mfma_f32_16x16x32_f16(a, Bf[jt][2][kk], acc[jt][2], 0, 0, 0);
      }
    }

    // gates (all lanes compute; lanes with m>=8 produce discarded garbage)
#pragma unroll
    for (int jt = 0; jt < 2; ++jt)
#pragma unroll
      for (int r = 0; r < 4; ++r) {
        const h4 xv = xc[jt * 4 + r];
        const float rg = frcp(1.0f + fexp2((float)xv[0] + acc[jt][0][r]));
        const float zg = frcp(1.0f + fexp2((float)xv[1] + acc[jt][1][r]));
        const float ng = fmaf(-2.0f, frcp(1.0f + fexp2(fmaf(rg, acc[jt][2][r], (float)xv[2]))), 1.0f);
        hprev[jt * 4 + r] = fmaf(zg, hprev[jt * 4 + r] - ng, ng);
      }

    // write new h (valid rows only)
    char* hw = (char*)hfrag + (p ^ 1) * 4096;
    if (lg < 2) {
#pragma unroll
      for (int jt = 0; jt < 2; ++jt)
#pragma unroll
        for (int r = 0; r < 4; ++r)
          *(f16*)(hw + wo[jt] + r * 16) = (f16)hprev[jt * 4 + r];
    }

#pragma unroll
    for (int i = 0; i < 8; ++i) xc[i] = xn[i];

    __syncthreads();
    p ^= 1;
  }

  if (lg < 2) {
#pragma unroll
    for (int jt = 0; jt < 2; ++jt)
#pragma unroll
      for (int r = 0; r < 4; ++r)
        feat[(b0 + lg * 4 + r) * En + dir * Hn + (j0 + jt * 16 + lr)] = hprev[jt * 4 + r];
  }
}

// ---------------- Kernel 3: adapter + LN + proj ----------------
// 256 blocks x 256 threads; 8 samples/block; wave wv: adapter for samples {2wv, 2wv+1},
// then proj o-range [wv*64, wv*64+64) via f16 MFMA (M=16 tile, rows 8-15 zero).
__launch_bounds__(256, 2)
__global__ void epi_k(const float* __restrict__ feat,
                      const int* __restrict__ lang_ids,
                      const float* __restrict__ down_w,
                      const float* __restrict__ down_b,
                      const float* __restrict__ up_w,
                      const float* __restrict__ up_b,
                      const float* __restrict__ ln_g,
                      const float* __restrict__ ln_b,
                      const float* __restrict__ proj_w,
                      const float* __restrict__ proj_b,
                      float* __restrict__ out) {
  const int tid = threadIdx.x;
  const int wv = tid >> 6, ln = tid & 63;
  const int b0 = blockIdx.x * 8;

  __shared__ float fl[8][En];
  __shared__ f16 yA[16][En + 8];

#pragma unroll
  for (int s = 0; s < 8; ++s) fl[s][tid] = feat[(b0 + s) * En + tid];
  {
    f16* z = &yA[0][0];
    for (int i = tid; i < 16 * (En + 8); i += 256) z[i] = (f16)0.f;
  }
  __syncthreads();

#pragma unroll 1
  for (int si = 0; si < 2; ++si) {
    const int s = wv * 2 + si;
    const int lang = lang_ids[b0 + s];

    const int d = ln & 31, hf = ln >> 5;
    const f4* dwv = (const f4*)(down_w + (lang * BNn + d) * En + hf * 128);
    const f4* fsv = (const f4*)&fl[s][hf * 128];
    float pacc = 0.f;
#pragma unroll
    for (int q = 0; q < 32; ++q) {
      f4 a = fsv[q], w = dwv[q];
      pacc = fmaf(a.x, w.x, pacc);
      pacc = fmaf(a.y, w.y, pacc);
      pacc = fmaf(a.z, w.z, pacc);
      pacc = fmaf(a.w, w.w, pacc);
    }
    pacc += __shfl_xor(pacc, 32);
    const float hv = pacc + down_b[lang * BNn + d];
    const float hid = 0.5f * hv * (1.0f + erff(hv * 0.70710678118f));

    float hh[32];
#pragma unroll
    for (int dd = 0; dd < 32; ++dd) hh[dd] = __shfl(hid, dd);

    const int e0 = ln * 4;
    float x[4];
    float s1 = 0.f, s2 = 0.f;
#pragma unroll
    for (int i = 0; i < 4; ++i) {
      const f4* ur = (const f4*)(up_w + (lang * En + e0 + i) * BNn);
      float a = 0.f;
#pragma unroll
      for (int q = 0; q < 8; ++q) {
        f4 u = ur[q];
        a = fmaf(hh[q * 4 + 0], u.x, a);
        a = fmaf(hh[q * 4 + 1], u.y, a);
        a = fmaf(hh[q * 4 + 2], u.z, a);
        a = fmaf(hh[q * 4 + 3], u.w, a);
      }
      x[i] = a + fl[s][e0 + i] + up_b[lang * En + e0 + i];
      s1 += x[i];
      s2 = fmaf(x[i], x[i], s2);
    }
#pragma unroll
    for (int off = 32; off >= 1; off >>= 1) {
      s1 += __shfl_xor(s1, off);
      s2 += __shfl_xor(s2, off);
    }
    const float mu = s1 * (1.0f / En);
    const float var = s2 * (1.0f / En) - mu * mu;
    const float rs = rsqrtf(var + 1e-5f);
#pragma unroll
    for (int i = 0; i < 4; ++i) {
      const float yv = (x[i] - mu) * rs * ln_g[lang * En + e0 + i] + ln_b[lang * En + e0 + i];
      yA[s][e0 + i] = (f16)yv;
    }
  }
  __syncthreads();

  const int lr = ln & 15, lg = ln >> 4;
  f4 acc[4];
#pragma unroll
  for (int tt = 0; tt < 4; ++tt) {
    const float pb = proj_b[wv * 64 + tt * 16 + lr];
    acc[tt] = (f4){pb, pb, pb, pb};
  }
#pragma unroll
  for (int kk = 0; kk < 8; ++kk) {
    h8 aF = *(const h8*)(&yA[lr][kk * 32 + lg * 8]);
#pragma unroll
    for (int tt = 0; tt < 4; ++tt) {
      const int o0 = wv * 64 + tt * 16;
      const float* pw = proj_w + (o0 + lr) * En + kk * 32 + lg * 8;
      h8 bF;
#pragma unroll
      for (int i = 0; i < 8; ++i) bF[i] = (f16)pw[i];
      acc[tt] = __builtin_amdgcn_mfma_f32_16x16x32_f16(aF, bF, acc[tt], 0, 0, 0);
    }
  }
  if (lg < 2) {
#pragma unroll
    for (int tt = 0; tt < 4; ++tt) {
      const int o0 = wv * 64 + tt * 16;
#pragma unroll
      for (int r = 0; r < 4; ++r)
        out[(b0 + lg * 4 + r) * On + o0 + lr] = acc[tt][r];
    }
  }
}

extern "C" void kernel_launch(void* const* d_in, const int* in_sizes, int n_in,
                              void* d_out, int out_size, void* d_ws, size_t ws_size,
                              hipStream_t stream) {
  const int* tokens = (const int*)d_in[0];
  const int* lang_ids = (const int*)d_in[1];
  const float* emb = (const float*)d_in[2];
  const float* w_ih_f = (const float*)d_in[3];
  const float* w_hh_f = (const float*)d_in[4];
  const float* b_ih_f = (const float*)d_in[5];
  const float* b_hh_f = (const float*)d_in[6];
  const float* w_ih_b = (const float*)d_in[7];
  const float* w_hh_b = (const float*)d_in[8];
  const float* b_ih_b = (const float*)d_in[9];
  const float* b_hh_b = (const float*)d_in[10];
  const float* down_w = (const float*)d_in[11];
  const float* down_b = (const float*)d_in[12];
  const float* up_w = (const float*)d_in[13];
  const float* up_b = (const float*)d_in[14];
  const float* ln_g = (const float*)d_in[15];
  const float* ln_b = (const float*)d_in[16];
  const float* proj_w = (const float*)d_in[17];
  const float* proj_b = (const float*)d_in[18];

  f16* xt = (f16*)d_ws;                                       // [2][256][128][4] f16 = 512KB
  float* feat = (float*)((char*)d_ws + 2 * Vn * Hn * 4 * 2);  // [2048][256] f32

  build_table_k<<<dim3(512), dim3(128), 0, stream>>>(emb, w_ih_f, b_ih_f, w_ih_b, b_ih_b, xt);
  gru_k<<<dim3(512), dim3(256), 0, stream>>>(tokens, w_hh_f, b_hh_f, w_hh_b, b_hh_b, xt, feat);
  epi_k<<<dim3(256), dim3(256), 0, stream>>>(feat, lang_ids, down_w, down_b, up_w, up_b,
                                             ln_g, ln_b, proj_w, proj_b, (float*)d_out);
}

// Round 5
// 131.100 us; speedup vs baseline: 1.6154x; 1.6154x over previous
//
#include <hip/hip_runtime.h>
#include <hip/hip_bf16.h>
#include <hip/hip_fp16.h>

#define Bn 2048
#define Tn 128
#define Vn 256
#define Cn 32
#define Hn 128
#define En 256
#define On 256
#define Gn 384
#define BNn 32

typedef _Float16 f16;
typedef __attribute__((ext_vector_type(8))) _Float16 h8;
typedef __attribute__((ext_vector_type(4))) _Float16 h4;
typedef __attribute__((ext_vector_type(4))) float f4;

#define LOG2E 1.4426950408889634f

__device__ __forceinline__ float fexp2(float x) { return __builtin_amdgcn_exp2f(x); }
__device__ __forceinline__ float frcp(float x) { return __builtin_amdgcn_rcpf(x); }

// ---------------- Kernel 1: packed scaled xp table ----------------
// xt[dir][v][j][4] = { -log2e*(xr+bir), -log2e*(xz+biz), 2log2e*(xn+bin), 0 }
__global__ void build_table_k(const float* __restrict__ emb,
                              const float* __restrict__ wf,
                              const float* __restrict__ bfv,
                              const float* __restrict__ wb,
                              const float* __restrict__ bbv,
                              f16* __restrict__ xt) {
  const int dir = blockIdx.x >> 8;
  const int v = blockIdx.x & 255;
  const int j = threadIdx.x;  // 128 threads
  const float* w = dir ? wb : wf;
  const float* bi = dir ? bbv : bfv;
  const float sc[3] = {-LOG2E, -LOG2E, 2.0f * LOG2E};
  h4 o;
  o[3] = (f16)0.f;
#pragma unroll
  for (int ga = 0; ga < 3; ++ga) {
    const int g = ga * Hn + j;
    float acc = bi[g];
    const f4* wr = (const f4*)(w + g * Cn);
    const f4* er = (const f4*)(emb + v * Cn);
#pragma unroll
    for (int q = 0; q < 8; ++q) {
      f4 wv = wr[q], ev = er[q];
      acc = fmaf(ev.x, wv.x, acc);
      acc = fmaf(ev.y, wv.y, acc);
      acc = fmaf(ev.z, wv.z, acc);
      acc = fmaf(ev.w, wv.w, acc);
    }
    o[ga] = (f16)(acc * sc[ga]);
  }
  *(h4*)&xt[((dir * Vn + v) * Hn + j) * 4] = o;
}

// ---------------- Kernel 2: bidirectional GRU ----------------
// 256 blocks: dir = bi&1, 16 samples/block (FULL 16x16 tiles), 8 waves x 16 j.
// h fragment-major: byte(k,m) = (k>>3)*256 + m*16 + (k&7)*2, double-buffered.
// xp prefetched into REGISTERS one step ahead; raw barrier does NOT drain vmcnt,
// so those L2 loads stay in flight across the barrier (consumed next step).
__launch_bounds__(512, 2)
__global__ void gru_k(const int* __restrict__ tokens,
                      const float* __restrict__ whhf,
                      const float* __restrict__ bhhf,
                      const float* __restrict__ whhb,
                      const float* __restrict__ bhhb,
                      const f16* __restrict__ xt,
                      float* __restrict__ feat) {
  const int dir = blockIdx.x & 1;
  const int b0 = (blockIdx.x >> 1) * 16;
  const int tid = threadIdx.x;
  const int wv = tid >> 6;   // 0..7
  const int ln = tid & 63;
  const int lr = ln & 15;    // A row / C col (j within tile)
  const int lg = ln >> 4;    // k-group; C rows m = lg*4+r (all 16 valid)
  const int j0 = wv * 16;
  const int j = j0 + lr;

  __shared__ f16 hfrag[2 * 2048];  // 2 x 4KB: [16 kq][16 m][8 ke]
  __shared__ int tokl[16 * 128];

  for (int i = tid; i < 16 * 128; i += 512)
    tokl[i] = tokens[(b0 + (i >> 7)) * Tn + (i & 127)];
  for (int i = tid; i < 2 * 2048; i += 512) hfrag[i] = (f16)0.f;

  const float* whh = dir ? whhb : whhf;
  const float* bhh = dir ? bhhb : bhhf;
  const f16* tab = xt + dir * (Vn * Hn * 4);

  // register-resident B frags, gate-scaled at load
  const float gsc[3] = {-LOG2E, -LOG2E, 2.0f * LOG2E};
  h8 Bf[3][4];
#pragma unroll
  for (int ga = 0; ga < 3; ++ga) {
    const float* wr = whh + (ga * Hn + j) * Hn + lg * 8;
#pragma unroll
    for (int kk = 0; kk < 4; ++kk) {
      h8 b;
#pragma unroll
      for (int i = 0; i < 8; ++i) b[i] = (f16)(wr[kk * 32 + i] * gsc[ga]);
      Bf[ga][kk] = b;
    }
  }
  const float bh0 = bhh[j] * (-LOG2E);
  const float bh1 = bhh[Hn + j] * (-LOG2E);
  const float bh2 = bhh[2 * Hn + j] * (2.0f * LOG2E);

  __syncthreads();  // tokl + hfrag zeros visible (full sync once)

  const int aoff = lg * 256 + lr * 16;                      // A-frag byte (+ kk*1024)
  const int woff = (j >> 3) * 256 + (j & 7) * 2 + lg * 64;  // h write byte (+ r*16)

  // prefetch xp for t=0 into registers
  h4 xc[4], xn[4];
  {
    const int tt = dir ? (Tn - 1) : 0;
#pragma unroll
    for (int r = 0; r < 4; ++r) {
      const int tok = tokl[(lg * 4 + r) * 128 + tt];
      xc[r] = *(const h4*)(tab + tok * 512 + j * 4);
    }
  }

  float hprev[4] = {0.f, 0.f, 0.f, 0.f};
  int p = 0;

#pragma unroll 1
  for (int t = 0; t < Tn; ++t) {
    // issue xp(t+1) loads; they remain in flight across this step's barrier
    const int tn = (t + 1 < Tn) ? (t + 1) : t;
    const int tt2 = dir ? (Tn - 1 - tn) : tn;
#pragma unroll
    for (int r = 0; r < 4; ++r) {
      const int tok = tokl[(lg * 4 + r) * 128 + tt2];
      xn[r] = *(const h4*)(tab + tok * 512 + j * 4);
    }

    // gh = h @ w_hh^T + b_hh
    const char* hb = (const char*)hfrag + p * 4096;
    f4 aR = {bh0, bh0, bh0, bh0};
    f4 aZ = {bh1, bh1, bh1, bh1};
    f4 aN = {bh2, bh2, bh2, bh2};
#pragma unroll
    for (int kk = 0; kk < 4; ++kk) {
      h8 a = *(const h8*)(hb + kk * 1024 + aoff);
      aR = __builtin_amdgcn_mfma_f32_16x16x32_f16(a, Bf[0][kk], aR, 0, 0, 0);
      aZ = __builtin_amdgcn_mfma_f32_16x16x32_f16(a, Bf[1][kk], aZ, 0, 0, 0);
      aN = __builtin_amdgcn_mfma_f32_16x16x32_f16(a, Bf[2][kk], aN, 0, 0, 0);
    }

    // gates; element (m = lg*4+r, j); xp & gh pre-scaled by -log2e / 2log2e
#pragma unroll
    for (int r = 0; r < 4; ++r) {
      const h4 xv = xc[r];
      const float rg = frcp(1.0f + fexp2((float)xv[0] + aR[r]));
      const float zg = frcp(1.0f + fexp2((float)xv[1] + aZ[r]));
      const float ng = fmaf(-2.0f, frcp(1.0f + fexp2(fmaf(rg, aN[r], (float)xv[2]))), 1.0f);
      hprev[r] = fmaf(zg, hprev[r] - ng, ng);
    }

    // write new h to the other buffer
    char* hw = (char*)hfrag + (p ^ 1) * 4096;
#pragma unroll
    for (int r = 0; r < 4; ++r)
      *(f16*)(hw + woff + r * 16) = (f16)hprev[r];

#pragma unroll
    for (int r = 0; r < 4; ++r) xc[r] = xn[r];

    // drain LDS ops only (NOT vmcnt) then barrier — xp loads stay in flight
    asm volatile("s_waitcnt lgkmcnt(0)\n\ts_barrier" ::: "memory");
    p ^= 1;
  }

  // final h is in registers
#pragma unroll
  for (int r = 0; r < 4; ++r)
    feat[(b0 + lg * 4 + r) * En + dir * Hn + j] = hprev[r];
}

// ---------------- Kernel 3: adapter + LN + proj ----------------
// 256 blocks x 256 threads; 8 samples/block; wave wv: adapter for samples {2wv, 2wv+1},
// then proj o-range [wv*64, wv*64+64) via f16 MFMA (M=16 tile, rows 8-15 zero).
__launch_bounds__(256, 2)
__global__ void epi_k(const float* __restrict__ feat,
                      const int* __restrict__ lang_ids,
                      const float* __restrict__ down_w,
                      const float* __restrict__ down_b,
                      const float* __restrict__ up_w,
                      const float* __restrict__ up_b,
                      const float* __restrict__ ln_g,
                      const float* __restrict__ ln_b,
                      const float* __restrict__ proj_w,
                      const float* __restrict__ proj_b,
                      float* __restrict__ out) {
  const int tid = threadIdx.x;
  const int wv = tid >> 6, ln = tid & 63;
  const int b0 = blockIdx.x * 8;

  __shared__ float fl[8][En];
  __shared__ f16 yA[16][En + 8];

#pragma unroll
  for (int s = 0; s < 8; ++s) fl[s][tid] = feat[(b0 + s) * En + tid];
  {
    f16* z = &yA[0][0];
    for (int i = tid; i < 16 * (En + 8); i += 256) z[i] = (f16)0.f;
  }
  __syncthreads();

#pragma unroll 1
  for (int si = 0; si < 2; ++si) {
    const int s = wv * 2 + si;
    const int lang = lang_ids[b0 + s];

    const int d = ln & 31, hf = ln >> 5;
    const f4* dwv = (const f4*)(down_w + (lang * BNn + d) * En + hf * 128);
    const f4* fsv = (const f4*)&fl[s][hf * 128];
    float pacc = 0.f;
#pragma unroll
    for (int q = 0; q < 32; ++q) {
      f4 a = fsv[q], w = dwv[q];
      pacc = fmaf(a.x, w.x, pacc);
      pacc = fmaf(a.y, w.y, pacc);
      pacc = fmaf(a.z, w.z, pacc);
      pacc = fmaf(a.w, w.w, pacc);
    }
    pacc += __shfl_xor(pacc, 32);
    const float hv = pacc + down_b[lang * BNn + d];
    const float hid = 0.5f * hv * (1.0f + erff(hv * 0.70710678118f));

    float hh[32];
#pragma unroll
    for (int dd = 0; dd < 32; ++dd) hh[dd] = __shfl(hid, dd);

    const int e0 = ln * 4;
    float x[4];
    float s1 = 0.f, s2 = 0.f;
#pragma unroll
    for (int i = 0; i < 4; ++i) {
      const f4* ur = (const f4*)(up_w + (lang * En + e0 + i) * BNn);
      float a = 0.f;
#pragma unroll
      for (int q = 0; q < 8; ++q) {
        f4 u = ur[q];
        a = fmaf(hh[q * 4 + 0], u.x, a);
        a = fmaf(hh[q * 4 + 1], u.y, a);
        a = fmaf(hh[q * 4 + 2], u.z, a);
        a = fmaf(hh[q * 4 + 3], u.w, a);
      }
      x[i] = a + fl[s][e0 + i] + up_b[lang * En + e0 + i];
      s1 += x[i];
      s2 = fmaf(x[i], x[i], s2);
    }
#pragma unroll
    for (int off = 32; off >= 1; off >>= 1) {
      s1 += __shfl_xor(s1, off);
      s2 += __shfl_xor(s2, off);
    }
    const float mu = s1 * (1.0f / En);
    const float var = s2 * (1.0f / En) - mu * mu;
    const float rs = rsqrtf(var + 1e-5f);
#pragma unroll
    for (int i = 0; i < 4; ++i) {
      const float yv = (x[i] - mu) * rs * ln_g[lang * En + e0 + i] + ln_b[lang * En + e0 + i];
      yA[s][e0 + i] = (f16)yv;
    }
  }
  __syncthreads();

  const int lr = ln & 15, lg = ln >> 4;
  f4 acc[4];
#pragma unroll
  for (int tt = 0; tt < 4; ++tt) {
    const float pb = proj_b[wv * 64 + tt * 16 + lr];
    acc[tt] = (f4){pb, pb, pb, pb};
  }
#pragma unroll
  for (int kk = 0; kk < 8; ++kk) {
    h8 aF = *(const h8*)(&yA[lr][kk * 32 + lg * 8]);
#pragma unroll
    for (int tt = 0; tt < 4; ++tt) {
      const int o0 = wv * 64 + tt * 16;
      const float* pw = proj_w + (o0 + lr) * En + kk * 32 + lg * 8;
      h8 bF;
#pragma unroll
      for (int i = 0; i < 8; ++i) bF[i] = (f16)pw[i];
      acc[tt] = __builtin_amdgcn_mfma_f32_16x16x32_f16(aF, bF, acc[tt], 0, 0, 0);
    }
  }
  if (lg < 2) {
#pragma unroll
    for (int tt = 0; tt < 4; ++tt) {
      const int o0 = wv * 64 + tt * 16;
#pragma unroll
      for (int r = 0; r < 4; ++r)
        out[(b0 + lg * 4 + r) * On + o0 + lr] = acc[tt][r];
    }
  }
}

extern "C" void kernel_launch(void* const* d_in, const int* in_sizes, int n_in,
                              void* d_out, int out_size, void* d_ws, size_t ws_size,
                              hipStream_t stream) {
  const int* tokens = (const int*)d_in[0];
  const int* lang_ids = (const int*)d_in[1];
  const float* emb = (const float*)d_in[2];
  const float* w_ih_f = (const float*)d_in[3];
  const float* w_hh_f = (const float*)d_in[4];
  const float* b_ih_f = (const float*)d_in[5];
  const float* b_hh_f = (const float*)d_in[6];
  const float* w_ih_b = (const float*)d_in[7];
  const float* w_hh_b = (const float*)d_in[8];
  const float* b_ih_b = (const float*)d_in[9];
  const float* b_hh_b = (const float*)d_in[10];
  const float* down_w = (const float*)d_in[11];
  const float* down_b = (const float*)d_in[12];
  const float* up_w = (const float*)d_in[13];
  const float* up_b = (const float*)d_in[14];
  const float* ln_g = (const float*)d_in[15];
  const float* ln_b = (const float*)d_in[16];
  const float* proj_w = (const float*)d_in[17];
  const float* proj_b = (const float*)d_in[18];

  f16* xt = (f16*)d_ws;                                       // [2][256][128][4] f16 = 512KB
  float* feat = (float*)((char*)d_ws + 2 * Vn * Hn * 4 * 2);  // [2048][256] f32

  build_table_k<<<dim3(512), dim3(128), 0, stream>>>(emb, w_ih_f, b_ih_f, w_ih_b, b_ih_b, xt);
  gru_k<<<dim3(256), dim3(512), 0, stream>>>(tokens, w_hh_f, b_hh_f, w_hh_b, b_hh_b, xt, feat);
  epi_k<<<dim3(256), dim3(256), 0, stream>>>(feat, lang_ids, down_w, down_b, up_w, up_b,
                                             ln_g, ln_b, proj_w, proj_b, (float*)d_out);
}